// Round 13
// baseline (185.360 us; speedup 1.0000x reference)
//
#include <hip/hip_runtime.h>
#include <stdint.h>

// Problem constants
//  SEQ=1024 (32x32), BSZ=8, EMBED=1024, KD=64, NDIM=16, V=64, R=16384, R2=16
//  DIRS=4, H=64, CDIM=4096

typedef __attribute__((ext_vector_type(8))) short short8;   // 8 bf16 (4 VGPRs)
typedef __attribute__((ext_vector_type(4))) float f32x4;    // MFMA accumulator

__device__ inline uint16_t f2bf(float f) {   // fp32 -> bf16 RNE
    uint32_t u = __float_as_uint(f);
    uint32_t r = (u + 0x7FFFu + ((u >> 16) & 1u)) >> 16;
    return (uint16_t)r;
}
__device__ inline float bf2f(uint16_t v) {
    return __uint_as_float((uint32_t)v << 16);
}
__device__ inline uint32_t packbf(float a, float b) {
    return (uint32_t)f2bf(a) | ((uint32_t)f2bf(b) << 16);
}

// ---------------------------------------------------------------------------
// K_pre (R5 form): 2054 blocks.
//   bx in [0,2048): transpose/pack half tiles (32 e x 128 r), LDS 16.5 KB.
//   bx in [2048,2054): one-shot tables LAg = -log2(sigmoid(A)), SBg = sigmoid(B).
// ---------------------------------------------------------------------------
__global__ __launch_bounds__(256) void k_pre(const float* __restrict__ x,
                                             uint16_t* __restrict__ xtb,
                                             const float* __restrict__ A,
                                             const float* __restrict__ B1,
                                             const float* __restrict__ B2,
                                             float* __restrict__ LAg,
                                             float* __restrict__ SBg) {
    __shared__ __align__(16) float shf[32 * 129];   // [e_local][r_local], 16.5 KB
    int bx = blockIdx.x;
    int t = threadIdx.x;

    if (bx < 2048) {
        int u = bx & 31, e0 = ((bx >> 5) & 31) * 32, r0 = (bx >> 10) * 128;
        {
            int c = t & 7, a = t >> 3;          // c: e-chunk lane, a: row 0..31
            const float* src = x + (size_t)(u * 256 + r0) * 1024 + e0 + c * 4;
            #pragma unroll
            for (int qq = 0; qq < 4; ++qq) {
                int r = qq * 32 + a;
                float4 v = *(const float4*)(src + (size_t)r * 1024);
                shf[(c * 4 + 0) * 129 + r] = v.x;
                shf[(c * 4 + 1) * 129 + r] = v.y;
                shf[(c * 4 + 2) * 129 + r] = v.z;
                shf[(c * 4 + 3) * 129 + r] = v.w;
            }
        }
        __syncthreads();
        {
            int e_local = t >> 3, b = t & 7;
            const float* row = shf + e_local * 129;
            int v0 = r0 >> 3;                   // 0 or 16
            uint32_t pk[8];
            #pragma unroll
            for (int k2 = 0; k2 < 8; ++k2)
                pk[k2] = packbf(row[(2 * k2) * 8 + b], row[(2 * k2 + 1) * 8 + b]);
            uint16_t* dst = xtb + (size_t)(e0 + e_local) * 8192 + u * 256 + b * 32 + v0;
            *(uint4*)dst       = make_uint4(pk[0], pk[1], pk[2], pk[3]);
            *(uint4*)(dst + 8) = make_uint4(pk[4], pk[5], pk[6], pk[7]);
        }
    } else {
        int i = bx - 2048;                          // 0..5
        int e = t * 4;
        if (i < 4) {
            float4 v = *(const float4*)(A + i * 1024 + e);
            float4 o;
            o.x = -log2f(1.0f + expf(-v.x));
            o.y = -log2f(1.0f + expf(-v.y));
            o.z = -log2f(1.0f + expf(-v.z));
            o.w = -log2f(1.0f + expf(-v.w));
            *(float4*)(LAg + i * 1024 + e) = o;
        } else {
            const float* Bs = (i == 4) ? B1 : B2;
            float4 v = *(const float4*)(Bs + e);
            float4 o;
            o.x = 1.0f / (1.0f + expf(-v.x));
            o.y = 1.0f / (1.0f + expf(-v.y));
            o.z = 1.0f / (1.0f + expf(-v.z));
            o.w = 1.0f / (1.0f + expf(-v.w));
            *(float4*)(SBg + (i - 4) * 1024 + e) = o;
        }
    }
}

// ---------------------------------------------------------------------------
// K_w (R12 best): one block per (d,p) — 2048 blocks.
// ---------------------------------------------------------------------------
__global__ __launch_bounds__(256) void k_w(const float* __restrict__ om,
                                           const float* __restrict__ LAg,
                                           const float* __restrict__ SBg,
                                           float* __restrict__ w) {
    __shared__ float ffl[16][4];      // selector indices as floats (this d)
    __shared__ float cfl[16][2];      // B-row cols 0,1 (this d)
    int bx = blockIdx.x;
    int d = bx >> 10, p = bx & 1023;
    int t = threadIdx.x;
    {
        int row_id = t >> 2, h = t & 3;               // 64 rows x 4 quarters
        int a = row_id >> 4, r2 = row_id & 15;
        const float* src = om + ((size_t)(d * 5 + a) * 16384 + p * 16 + r2) * 64 + h * 16;
        float s = 0.0f;
        #pragma unroll
        for (int q = 0; q < 4; ++q) {
            float4 v = *(const float4*)(src + q * 4);
            float jb = (float)(h * 16 + q * 4);
            s = __builtin_fmaf(v.x, jb,
                __builtin_fmaf(v.y, jb + 1.0f,
                __builtin_fmaf(v.z, jb + 2.0f,
                __builtin_fmaf(v.w, jb + 3.0f, s))));
        }
        s += __shfl_xor(s, 1);
        s += __shfl_xor(s, 2);
        if (h == 0) ffl[r2][a] = s;
        if (t < 16) {
            const float* c = om + ((size_t)(d * 5 + 4) * 16384 + p * 16 + t) * 64;
            cfl[t][0] = c[0];
            cfl[t][1] = c[1];
        }
    }
    __syncthreads();

    int j0 = t * 4;
    float L0[4], L1[4], L2[4], L3[4], B0v[4], B1v[4], acc[4];
    #pragma unroll
    for (int a = 0; a < 4; ++a) {
        float* La = (a == 0) ? L0 : (a == 1) ? L1 : (a == 2) ? L2 : L3;
        float4 u0 = *(const float4*)(LAg + a * 1024 + j0);
        La[0] = u0.x; La[1] = u0.y; La[2] = u0.z; La[3] = u0.w;
    }
    {
        float4 u0 = *(const float4*)(SBg + j0);
        float4 v0 = *(const float4*)(SBg + 1024 + j0);
        B0v[0] = u0.x; B0v[1] = u0.y; B0v[2] = u0.z; B0v[3] = u0.w;
        B1v[0] = v0.x; B1v[1] = v0.y; B1v[2] = v0.z; B1v[3] = v0.w;
    }
    #pragma unroll
    for (int jj = 0; jj < 4; ++jj) acc[jj] = 0.0f;

    #pragma unroll
    for (int r2 = 0; r2 < 16; ++r2) {
        float f0 = ffl[r2][0];
        float f1 = ffl[r2][1];
        float f2 = ffl[r2][2];
        float f3 = ffl[r2][3];
        float c0 = cfl[r2][0];
        float c1 = cfl[r2][1];
        #pragma unroll
        for (int jj = 0; jj < 4; ++jj) {
            float ex = __builtin_fmaf(f3, L3[jj],
                       __builtin_fmaf(f2, L2[jj],
                       __builtin_fmaf(f1, L1[jj], f0 * L0[jj])));
            float bs = __builtin_fmaf(c1, B1v[jj], c0 * B0v[jj]);
            acc[jj] = __builtin_fmaf(exp2f(ex), bs, acc[jj]);
        }
    }
    float* dst = w + (size_t)(d * 1024 + p) * 1024 + j0;
    *(float4*)dst = make_float4(acc[0], acc[1], acc[2], acc[3]);
}

// ---------------------------------------------------------------------------
// K_kd: kd4b[dir][e][p] (bf16) = boundary(p) * sum_{d,n} w*C/4
// ---------------------------------------------------------------------------
__global__ __launch_bounds__(256) void k_kd(const float* __restrict__ w,
                                            const float* __restrict__ C1,
                                            const float* __restrict__ C2,
                                            uint16_t* __restrict__ kd4b) {
    __shared__ float Wl[128 * 33];
    __shared__ float Ctl[32 * 65];
    int kap = blockIdx.x;
    int p0 = blockIdx.y * 128;
    int dir = kap >> 4, m = kap & 15;
    int t = threadIdx.x;

    {
        int off = (t & 3) * 4;
        #pragma unroll
        for (int rep = 0; rep < 4; ++rep) {
            int row_id = rep * 64 + (t >> 2);   // 0..255 = 2 d x 128 p
            int d = row_id >> 7, pp = row_id & 127;
            const float* src = w + ((size_t)(d * 1024 + p0 + pp) * 64 + kap) * 16 + off;
            float4 v = *(const float4*)src;
            float* dstl = Wl + pp * 33 + d * 16 + off;
            dstl[0] = v.x; dstl[1] = v.y; dstl[2] = v.z; dstl[3] = v.w;
        }
    }
    if (t < 128) {
        int d = t >> 6, h = t & 63;
        const float* Cd = d ? C2 : C1;
        const float* src = Cd + (size_t)(h * 64 + kap) * 16;
        #pragma unroll
        for (int q = 0; q < 16; ++q)
            Ctl[(d * 16 + q) * 65 + h] = src[q] * 0.25f;
    }
    __syncthreads();

    int ph = t & 15, hq = t >> 4;
    int pl = ph * 8, h0 = hq * 4;
    float acc[8][4];
    #pragma unroll
    for (int i = 0; i < 8; ++i)
        { acc[i][0] = acc[i][1] = acc[i][2] = acc[i][3] = 0.0f; }

    for (int k = 0; k < 32; ++k) {
        float c0 = Ctl[k * 65 + h0 + 0];
        float c1 = Ctl[k * 65 + h0 + 1];
        float c2 = Ctl[k * 65 + h0 + 2];
        float c3 = Ctl[k * 65 + h0 + 3];
        #pragma unroll
        for (int i = 0; i < 8; ++i) {
            float wv = Wl[(pl + i) * 33 + k];
            acc[i][0] += wv * c0; acc[i][1] += wv * c1;
            acc[i][2] += wv * c2; acc[i][3] += wv * c3;
        }
    }
    #pragma unroll
    for (int j = 0; j < 4; ++j) {
        int h = h0 + j;
        uint32_t pk[4];
        #pragma unroll
        for (int qq = 0; qq < 4; ++qq) {
            float v0, v1;
            #pragma unroll
            for (int z = 0; z < 2; ++z) {
                int p = p0 + pl + qq * 2 + z;
                int ii = p >> 5, jj = p & 31;
                float f = ((ii == 0) != (jj == 0)) ? 2.0f : 1.0f;
                float val = acc[qq * 2 + z][j] * f;
                if (z == 0) v0 = val; else v1 = val;
            }
            pk[qq] = packbf(v0, v1);
        }
        uint16_t* dst = kd4b + ((size_t)(dir * 1024 + h * 16 + m)) * 1024 + p0 + pl;
        *(uint4*)dst = make_uint4(pk[0], pk[1], pk[2], pk[3]);
    }
}

// ---------------------------------------------------------------------------
// K_conv (MFMA): row-pair packed + static schedule (R10/R12 math), NEW (R13):
//   B-fragments read DIRECTLY from global xtb (L2-resident 16KB/e region) —
//   removes the 16 KB Xt LDS stage, LDS 40 -> 24.6 KB => 6 blocks/CU.
//   u = -1 zero-fragment via clamped load + per-lane select-0 (no zptr).
//   Byte layout identical: xtb_e + u*512 + boff == old xtl + u*512 + boff.
// ---------------------------------------------------------------------------
__global__ __launch_bounds__(256) void k_conv(const uint16_t* __restrict__ xtb,
                                              const uint16_t* __restrict__ kd4b,
                                              uint16_t* __restrict__ ytb) {
    __shared__ __align__(16) char smem[24576];  // Krev only
    const int KROW = 768;   // 8 s-rows * 96 B
    const int SROW = 96;    // 48 shorts per s-row, no pad

    int e = blockIdx.x;
    int t = threadIdx.x;
    int lane = t & 63, wv = t >> 6;
    int n = lane & 15, q = lane >> 4, nn = n & 7, hi = n >> 3;

    // zero Krev (24576 B = 1536 x 16B)
    {
        f32x4 z = {0.f, 0.f, 0.f, 0.f};
        #pragma unroll
        for (int k = 0; k < 6; ++k)
            *(f32x4*)(smem + (t + k * 256) * 16) = z;
    }
    // flip-sum 4 kernel pixels
    int pi = t >> 3, pj = (t & 7) * 4;
    float s0, s1, s2, s3;
    {
        const uint16_t* b0 = kd4b + (size_t)e * 1024;
        ushort4 a0 = *(const ushort4*)(b0 + pi * 32 + pj);
        ushort4 a1 = *(const ushort4*)(b0 + (1 << 20) + (31 - pi) * 32 + pj);
        ushort4 a2 = *(const ushort4*)(b0 + (2 << 20) + pi * 32 + (28 - pj));
        ushort4 a3 = *(const ushort4*)(b0 + (3 << 20) + (31 - pi) * 32 + (28 - pj));
        s0 = bf2f(a0.x) + bf2f(a1.x) + bf2f(a2.w) + bf2f(a3.w);
        s1 = bf2f(a0.y) + bf2f(a1.y) + bf2f(a2.z) + bf2f(a3.z);
        s2 = bf2f(a0.z) + bf2f(a1.z) + bf2f(a2.y) + bf2f(a3.y);
        s3 = bf2f(a0.w) + bf2f(a1.w) + bf2f(a2.x) + bf2f(a3.x);
    }
    __syncthreads();   // zeroing complete

    // scatter into 8 shift-staggered reversed copies
    {
        uint16_t k0 = f2bf(s0), k1 = f2bf(s1), k2 = f2bf(s2), k3 = f2bf(s3);
        #pragma unroll
        for (int s = 0; s < 8; ++s) {
            uint16_t* row = (uint16_t*)(smem + pi * KROW + s * SROW);
            int c = 31 + s - pj;           // c-3..c within [s, 31+s] ⊂ [0,48)
            row[c]     = k0;
            row[c - 1] = k1;
            row[c - 2] = k2;
            row[c - 3] = k3;
        }
    }
    __syncthreads();

    // lane offsets into Krev rows (16B-aligned)
    int A0 = n - 8 * q;          // tile0 leading index; < -8 => all-zero fragment
    int A1 = A0 + 16;            // tile1 leading index
    int sh1 = (A1 + 9) & 7;
    int off1 = sh1 * SROW + (31 + sh1 - A1) * 2;
    int off0;
    if (A0 >= -8) {
        int sh0 = (A0 + 9) & 7;
        off0 = sh0 * SROW + (31 + sh0 - A0) * 2;
    } else {
        off0 = 80;               // row 0 (s=0), c=40..47: guaranteed-zero 16B
    }
    // global B base for this block's e (byte-identical to old LDS Xt layout)
    const char* xg = (const char*)xtb + (size_t)e * 16384 + nn * 64 + q * 16;
    const short8 zfrag = {0, 0, 0, 0, 0, 0, 0, 0};

    f32x4 acc0[4], acc1[4];
    #pragma unroll
    for (int ii = 0; ii < 4; ++ii) {
        acc0[ii] = (f32x4){0.f, 0.f, 0.f, 0.f};
        acc1[ii] = (f32x4){0.f, 0.f, 0.f, 0.f};
    }

    // Phase A: di = j in [0, 2wv+1]; all 4 ii active.
    #pragma unroll
    for (int j = 0; j < 8; ++j) {
        if (j <= 2 * wv + 1) {                       // wave-uniform
            const char* krow = smem + j * KROW;
            short8 a0 = *(const short8*)(krow + off0);
            short8 a1 = *(const short8*)(krow + off1);
            {   // ii = 0: u may be -1 (j = 2wv+1, hi = 0)
                int u = 2 * wv + hi - j;
                short8 bb = *(const short8*)(xg + (u >= 0 ? u : 0) * 512);
                if (u < 0) bb = zfrag;
                acc0[0] = __builtin_amdgcn_mfma_f32_16x16x32_bf16(a0, bb, acc0[0], 0, 0, 0);
                acc1[0] = __builtin_amdgcn_mfma_f32_16x16x32_bf16(a1, bb, acc1[0], 0, 0, 0);
            }
            #pragma unroll
            for (int ii = 1; ii < 4; ++ii) {         // u >= 7 always
                int u = 2 * wv + 8 * ii + hi - j;
                short8 bb = *(const short8*)(xg + u * 512);
                acc0[ii] = __builtin_amdgcn_mfma_f32_16x16x32_bf16(a0, bb, acc0[ii], 0, 0, 0);
                acc1[ii] = __builtin_amdgcn_mfma_f32_16x16x32_bf16(a1, bb, acc1[ii], 0, 0, 0);
            }
        }
    }
    // Phase B: b = 1..3, m = 0..7: di = 2wv + 8b - 6 + m; ii = b..3 active.
    #pragma unroll
    for (int b = 1; b <= 3; ++b) {
        #pragma unroll
        for (int m = 0; m < 8; ++m) {
            int di = 2 * wv + 8 * b - 6 + m;
            const char* krow = smem + di * KROW;
            short8 a0 = *(const short8*)(krow + off0);
            short8 a1 = *(const short8*)(krow + off1);
            #pragma unroll
            for (int ii = b; ii < 4; ++ii) {
                int u = 8 * (ii - b) + 6 + hi - m;   // < 0 only at ii==b, m==7, hi==0
                short8 bb;
                if ((ii == b) && (m == 7)) {         // static site: u = hi - 1
                    bb = *(const short8*)(xg + (u >= 0 ? u : 0) * 512);
                    if (u < 0) bb = zfrag;
                } else {
                    bb = *(const short8*)(xg + u * 512);
                }
                acc0[ii] = __builtin_amdgcn_mfma_f32_16x16x32_bf16(a0, bb, acc0[ii], 0, 0, 0);
                acc1[ii] = __builtin_amdgcn_mfma_f32_16x16x32_bf16(a1, bb, acc1[ii], 0, 0, 0);
            }
        }
    }

    // epilogue: ALL lanes store; row_out = 2wv + 8ii + hi, batch nn.
    {
        uint16_t* base = ytb + ((size_t)(nn * 1024 + e)) * 1024 + q * 4;
        #pragma unroll
        for (int ii = 0; ii < 4; ++ii) {
            int ro = 2 * wv + 8 * ii + hi;
            uint2 w0 = make_uint2(packbf(acc0[ii][0], acc0[ii][1]),
                                  packbf(acc0[ii][2], acc0[ii][3]));
            uint2 w1 = make_uint2(packbf(acc1[ii][0], acc1[ii][1]),
                                  packbf(acc1[ii][2], acc1[ii][3]));
            *(uint2*)(base + ro * 32)      = w0;
            *(uint2*)(base + ro * 32 + 16) = w1;
        }
    }
}

// ---------------------------------------------------------------------------
// K_t2: out[p][b][e] = ytb[b][e][p] + x[p][b][e]*omega[e]
// ---------------------------------------------------------------------------
__global__ __launch_bounds__(256) void k_t2(const uint16_t* __restrict__ ytb,
                                            const float* __restrict__ x,
                                            const float* __restrict__ omega,
                                            float* __restrict__ out) {
    __shared__ float lds[32 * 130];   // [e][pl], pad 130 (8B-aligned float2)
    int e0 = blockIdx.x * 32, p0 = blockIdx.y * 128, b = blockIdx.z;
    int t = threadIdx.x;
    {
        int a = t >> 3, c = t & 7;          // a: e-row 0..31, c: 128B chunk
        const uint16_t* src = ytb + (size_t)(b * 1024 + e0 + a) * 1024 + p0;
        float* dst = lds + a * 130;
        #pragma unroll
        for (int rep = 0; rep < 2; ++rep) {
            int off = (c + rep * 8) * 8;    // p offset, 8 p per uint4
            uint4 v = *(const uint4*)(src + off);
            uint32_t ww[4] = {v.x, v.y, v.z, v.w};
            #pragma unroll
            for (int k = 0; k < 4; ++k) {
                float2 f;
                f.x = bf2f((uint16_t)(ww[k] & 0xFFFFu));
                f.y = bf2f((uint16_t)(ww[k] >> 16));
                *(float2*)(dst + off + k * 2) = f;
            }
        }
    }
    __syncthreads();
    int pl = t >> 1, eh = (t & 1) * 16;
    int p = p0 + pl;
    const float* xs = x + ((size_t)(p * 8 + b)) * 1024 + e0 + eh;
    float* os = out + ((size_t)(p * 8 + b)) * 1024 + e0 + eh;
    #pragma unroll
    for (int qq = 0; qq < 4; ++qq) {
        float4 xv = *(const float4*)(xs + qq * 4);
        int eb = eh + qq * 4;
        float4 ov;
        ov.x = lds[(eb + 0) * 130 + pl] + xv.x * omega[e0 + eb + 0];
        ov.y = lds[(eb + 1) * 130 + pl] + xv.y * omega[e0 + eb + 1];
        ov.z = lds[(eb + 2) * 130 + pl] + xv.z * omega[e0 + eb + 2];
        ov.w = lds[(eb + 3) * 130 + pl] + xv.w * omega[e0 + eb + 3];
        *(float4*)(os + qq * 4) = ov;
    }
}

// ---------------------------------------------------------------------------
extern "C" void kernel_launch(void* const* d_in, const int* in_sizes, int n_in,
                              void* d_out, int out_size, void* d_ws, size_t ws_size,
                              hipStream_t stream) {
    (void)in_sizes; (void)n_in; (void)out_size; (void)ws_size;
    const float* x   = (const float*)d_in[0];
    const float* A   = (const float*)d_in[1];
    const float* B1  = (const float*)d_in[2];
    const float* B2  = (const float*)d_in[3];
    const float* C1  = (const float*)d_in[4];
    const float* C2  = (const float*)d_in[5];
    const float* omg = (const float*)d_in[6];
    const float* om  = (const float*)d_in[7];
    float* out = (float*)d_out;

    float* ws  = (float*)d_ws;
    uint16_t* xtb  = (uint16_t*)ws;                     // 16 MB
    uint16_t* kd4b = (uint16_t*)(ws + 4194304);         // 8 MB
    uint16_t* ytb  = (uint16_t*)(ws + 6291456);         // 16 MB
    float* w       = ws + 10485760;                     // 8 MB
    float* LAg     = ws + 4194304 + 65536;              // 16 KB  [4][1024]
    float* SBg     = ws + 4194304 + 69632;              // 8 KB   [2][1024]

    k_pre <<<2054, 256, 0, stream>>>(x, xtb, A, B1, B2, LAg, SBg);
    k_w   <<<2048, 256, 0, stream>>>(om, LAg, SBg, w);
    k_kd  <<<dim3(64, 8), 256, 0, stream>>>(w, C1, C2, kd4b);
    k_conv<<<1024, 256, 0, stream>>>(xtb, kd4b, ytb);
    k_t2  <<<dim3(32, 8, 8), 256, 0, stream>>>(ytb, x, omg, out);
}

// Round 14
// 181.603 us; speedup vs baseline: 1.0207x; 1.0207x over previous
//
#include <hip/hip_runtime.h>
#include <stdint.h>

// Problem constants
//  SEQ=1024 (32x32), BSZ=8, EMBED=1024, KD=64, NDIM=16, V=64, R=16384, R2=16
//  DIRS=4, H=64, CDIM=4096

typedef __attribute__((ext_vector_type(8))) short short8;   // 8 bf16 (4 VGPRs)
typedef __attribute__((ext_vector_type(4))) float f32x4;    // MFMA accumulator

__device__ inline uint16_t f2bf(float f) {   // fp32 -> bf16 RNE
    uint32_t u = __float_as_uint(f);
    uint32_t r = (u + 0x7FFFu + ((u >> 16) & 1u)) >> 16;
    return (uint16_t)r;
}
__device__ inline float bf2f(uint16_t v) {
    return __uint_as_float((uint32_t)v << 16);
}
__device__ inline uint32_t packbf(float a, float b) {
    return (uint32_t)f2bf(a) | ((uint32_t)f2bf(b) << 16);
}

// ---------------------------------------------------------------------------
// K_front4: 4096 blocks, HBM-bound transpose & VALU-bound w interleaved so
// both pipes co-reside per CU (m114 MFMA/VALU/VMEM overlap).
//   even bx: transpose/pack half tiles (32 e x 128 r), LDS 16.5 KB.
//   odd bx:  R12's d-split w kernel for (d,p) = (bx>>1)>>10, (bx>>1)&1023,
//     with tables computed inline via NATIVE v_exp/v_log/v_rcp (~4 ops per
//     value, 24 values/thread) — the two prior merge failures (R4/R9) were
//     caused by 33 KB LDS coupling + ~20-op libm table sequences; both gone.
// ---------------------------------------------------------------------------
__global__ __launch_bounds__(256) void k_front4(const float* __restrict__ x,
                                                uint16_t* __restrict__ xtb,
                                                const float* __restrict__ om,
                                                const float* __restrict__ A,
                                                const float* __restrict__ B1,
                                                const float* __restrict__ B2,
                                                float* __restrict__ w) {
    __shared__ __align__(16) float shf[32 * 129];   // transpose tile / ffl+cfl
    const float LOG2E = 1.44269504088896f;
    int bx = blockIdx.x;
    int t = threadIdx.x;

    if ((bx & 1) == 0) {
        // ---- transpose/pack, tidx = bx>>1 in [0,2048) ----
        int tidx = bx >> 1;
        int u = tidx & 31, e0 = ((tidx >> 5) & 31) * 32, r0 = (tidx >> 10) * 128;
        {
            int c = t & 7, a = t >> 3;          // c: e-chunk lane, a: row 0..31
            const float* src = x + (size_t)(u * 256 + r0) * 1024 + e0 + c * 4;
            #pragma unroll
            for (int qq = 0; qq < 4; ++qq) {
                int r = qq * 32 + a;
                float4 v = *(const float4*)(src + (size_t)r * 1024);
                shf[(c * 4 + 0) * 129 + r] = v.x;
                shf[(c * 4 + 1) * 129 + r] = v.y;
                shf[(c * 4 + 2) * 129 + r] = v.z;
                shf[(c * 4 + 3) * 129 + r] = v.w;
            }
        }
        __syncthreads();
        {
            int e_local = t >> 3, b = t & 7;
            const float* row = shf + e_local * 129;
            int v0 = r0 >> 3;                   // 0 or 16
            uint32_t pk[8];
            #pragma unroll
            for (int k2 = 0; k2 < 8; ++k2)
                pk[k2] = packbf(row[(2 * k2) * 8 + b], row[(2 * k2 + 1) * 8 + b]);
            uint16_t* dst = xtb + (size_t)(e0 + e_local) * 8192 + u * 256 + b * 32 + v0;
            *(uint4*)dst       = make_uint4(pk[0], pk[1], pk[2], pk[3]);
            *(uint4*)(dst + 8) = make_uint4(pk[4], pk[5], pk[6], pk[7]);
        }
    } else {
        // ---- w for (d,p), R12 structure + inline native-intrinsic tables ----
        int wid = bx >> 1;
        int d = wid >> 10, p = wid & 1023;
        float* ffl = shf;                 // [16][4]
        float* cfl = shf + 64;            // [16][2]
        {
            int row_id = t >> 2, h = t & 3;               // 64 rows x 4 quarters
            int a = row_id >> 4, r2 = row_id & 15;
            const float* src = om + ((size_t)(d * 5 + a) * 16384 + p * 16 + r2) * 64 + h * 16;
            float s = 0.0f;
            #pragma unroll
            for (int q = 0; q < 4; ++q) {
                float4 v = *(const float4*)(src + q * 4);
                float jb = (float)(h * 16 + q * 4);
                s = __builtin_fmaf(v.x, jb,
                    __builtin_fmaf(v.y, jb + 1.0f,
                    __builtin_fmaf(v.z, jb + 2.0f,
                    __builtin_fmaf(v.w, jb + 3.0f, s))));
            }
            s += __shfl_xor(s, 1);
            s += __shfl_xor(s, 2);
            if (h == 0) ffl[r2 * 4 + a] = s;
            if (t < 16) {
                const float* c = om + ((size_t)(d * 5 + 4) * 16384 + p * 16 + t) * 64;
                cfl[t * 2 + 0] = c[0];
                cfl[t * 2 + 1] = c[1];
            }
        }

        // inline tables: L = -log2(1+exp(-a)), s = sigmoid(b); native trans ops
        int j0 = t * 4;
        float L0[4], L1[4], L2[4], L3[4], B0v[4], B1v[4], acc[4];
        #pragma unroll
        for (int a = 0; a < 4; ++a) {
            float* La = (a == 0) ? L0 : (a == 1) ? L1 : (a == 2) ? L2 : L3;
            float4 v = *(const float4*)(A + a * 1024 + j0);
            float tv[4] = {v.x, v.y, v.z, v.w};
            #pragma unroll
            for (int k = 0; k < 4; ++k) {
                float ex = __builtin_amdgcn_exp2f(-tv[k] * LOG2E);   // e^-a
                La[k] = -__builtin_amdgcn_logf(1.0f + ex);           // -log2(1+e^-a)
            }
        }
        {
            float4 u0 = *(const float4*)(B1 + j0);
            float4 v0 = *(const float4*)(B2 + j0);
            float t1v[4] = {u0.x, u0.y, u0.z, u0.w};
            float t2v[4] = {v0.x, v0.y, v0.z, v0.w};
            #pragma unroll
            for (int k = 0; k < 4; ++k) {
                B0v[k] = __builtin_amdgcn_rcpf(1.0f + __builtin_amdgcn_exp2f(-t1v[k] * LOG2E));
                B1v[k] = __builtin_amdgcn_rcpf(1.0f + __builtin_amdgcn_exp2f(-t2v[k] * LOG2E));
            }
        }
        #pragma unroll
        for (int jj = 0; jj < 4; ++jj) acc[jj] = 0.0f;
        __syncthreads();

        #pragma unroll
        for (int r2 = 0; r2 < 16; ++r2) {
            float f0 = ffl[r2 * 4 + 0];
            float f1 = ffl[r2 * 4 + 1];
            float f2 = ffl[r2 * 4 + 2];
            float f3 = ffl[r2 * 4 + 3];
            float c0 = cfl[r2 * 2 + 0];
            float c1 = cfl[r2 * 2 + 1];
            #pragma unroll
            for (int jj = 0; jj < 4; ++jj) {
                float ex = __builtin_fmaf(f3, L3[jj],
                           __builtin_fmaf(f2, L2[jj],
                           __builtin_fmaf(f1, L1[jj], f0 * L0[jj])));
                float bs = __builtin_fmaf(c1, B1v[jj], c0 * B0v[jj]);
                acc[jj] = __builtin_fmaf(exp2f(ex), bs, acc[jj]);
            }
        }
        float* dst = w + (size_t)(d * 1024 + p) * 1024 + j0;
        *(float4*)dst = make_float4(acc[0], acc[1], acc[2], acc[3]);
    }
}

// ---------------------------------------------------------------------------
// K_kd: kd4b[dir][e][p] (bf16) = boundary(p) * sum_{d,n} w*C/4
// ---------------------------------------------------------------------------
__global__ __launch_bounds__(256) void k_kd(const float* __restrict__ w,
                                            const float* __restrict__ C1,
                                            const float* __restrict__ C2,
                                            uint16_t* __restrict__ kd4b) {
    __shared__ float Wl[128 * 33];
    __shared__ float Ctl[32 * 65];
    int kap = blockIdx.x;
    int p0 = blockIdx.y * 128;
    int dir = kap >> 4, m = kap & 15;
    int t = threadIdx.x;

    {
        int off = (t & 3) * 4;
        #pragma unroll
        for (int rep = 0; rep < 4; ++rep) {
            int row_id = rep * 64 + (t >> 2);   // 0..255 = 2 d x 128 p
            int d = row_id >> 7, pp = row_id & 127;
            const float* src = w + ((size_t)(d * 1024 + p0 + pp) * 64 + kap) * 16 + off;
            float4 v = *(const float4*)src;
            float* dstl = Wl + pp * 33 + d * 16 + off;
            dstl[0] = v.x; dstl[1] = v.y; dstl[2] = v.z; dstl[3] = v.w;
        }
    }
    if (t < 128) {
        int d = t >> 6, h = t & 63;
        const float* Cd = d ? C2 : C1;
        const float* src = Cd + (size_t)(h * 64 + kap) * 16;
        #pragma unroll
        for (int q = 0; q < 16; ++q)
            Ctl[(d * 16 + q) * 65 + h] = src[q] * 0.25f;
    }
    __syncthreads();

    int ph = t & 15, hq = t >> 4;
    int pl = ph * 8, h0 = hq * 4;
    float acc[8][4];
    #pragma unroll
    for (int i = 0; i < 8; ++i)
        { acc[i][0] = acc[i][1] = acc[i][2] = acc[i][3] = 0.0f; }

    for (int k = 0; k < 32; ++k) {
        float c0 = Ctl[k * 65 + h0 + 0];
        float c1 = Ctl[k * 65 + h0 + 1];
        float c2 = Ctl[k * 65 + h0 + 2];
        float c3 = Ctl[k * 65 + h0 + 3];
        #pragma unroll
        for (int i = 0; i < 8; ++i) {
            float wv = Wl[(pl + i) * 33 + k];
            acc[i][0] += wv * c0; acc[i][1] += wv * c1;
            acc[i][2] += wv * c2; acc[i][3] += wv * c3;
        }
    }
    #pragma unroll
    for (int j = 0; j < 4; ++j) {
        int h = h0 + j;
        uint32_t pk[4];
        #pragma unroll
        for (int qq = 0; qq < 4; ++qq) {
            float v0, v1;
            #pragma unroll
            for (int z = 0; z < 2; ++z) {
                int p = p0 + pl + qq * 2 + z;
                int ii = p >> 5, jj = p & 31;
                float f = ((ii == 0) != (jj == 0)) ? 2.0f : 1.0f;
                float val = acc[qq * 2 + z][j] * f;
                if (z == 0) v0 = val; else v1 = val;
            }
            pk[qq] = packbf(v0, v1);
        }
        uint16_t* dst = kd4b + ((size_t)(dir * 1024 + h * 16 + m)) * 1024 + p0 + pl;
        *(uint4*)dst = make_uint4(pk[0], pk[1], pk[2], pk[3]);
    }
}

// ---------------------------------------------------------------------------
// K_conv (MFMA): R12 form (best, 184.7) — row-pair packed, static schedule,
// LDS-staged Xt, zptr zero-fragment.
// ---------------------------------------------------------------------------
__global__ __launch_bounds__(256) void k_conv(const uint16_t* __restrict__ xtb,
                                              const uint16_t* __restrict__ kd4b,
                                              uint16_t* __restrict__ ytb) {
    __shared__ __align__(16) char smem[24576 + 16384];  // Krev + Xt
    const int KROW = 768;   // 8 s-rows * 96 B
    const int SROW = 96;    // 48 shorts per s-row, no pad
    char* xtl = smem + 24576;

    int e = blockIdx.x;
    int t = threadIdx.x;
    int lane = t & 63, wv = t >> 6;
    int n = lane & 15, q = lane >> 4, nn = n & 7, hi = n >> 3;

    {
        f32x4 z = {0.f, 0.f, 0.f, 0.f};
        #pragma unroll
        for (int k = 0; k < 6; ++k)
            *(f32x4*)(smem + (t + k * 256) * 16) = z;
    }
    {
        const uint4* src = (const uint4*)(xtb + (size_t)e * 8192);
        #pragma unroll
        for (int r = 0; r < 4; ++r) {
            uint4 v = src[r * 256 + t];
            *(uint4*)(xtl + (r * 256 + t) * 16) = v;
        }
    }
    int pi = t >> 3, pj = (t & 7) * 4;
    float s0, s1, s2, s3;
    {
        const uint16_t* b0 = kd4b + (size_t)e * 1024;
        ushort4 a0 = *(const ushort4*)(b0 + pi * 32 + pj);
        ushort4 a1 = *(const ushort4*)(b0 + (1 << 20) + (31 - pi) * 32 + pj);
        ushort4 a2 = *(const ushort4*)(b0 + (2 << 20) + pi * 32 + (28 - pj));
        ushort4 a3 = *(const ushort4*)(b0 + (3 << 20) + (31 - pi) * 32 + (28 - pj));
        s0 = bf2f(a0.x) + bf2f(a1.x) + bf2f(a2.w) + bf2f(a3.w);
        s1 = bf2f(a0.y) + bf2f(a1.y) + bf2f(a2.z) + bf2f(a3.z);
        s2 = bf2f(a0.z) + bf2f(a1.z) + bf2f(a2.y) + bf2f(a3.y);
        s3 = bf2f(a0.w) + bf2f(a1.w) + bf2f(a2.x) + bf2f(a3.x);
    }
    __syncthreads();

    {
        uint16_t k0 = f2bf(s0), k1 = f2bf(s1), k2 = f2bf(s2), k3 = f2bf(s3);
        #pragma unroll
        for (int s = 0; s < 8; ++s) {
            uint16_t* row = (uint16_t*)(smem + pi * KROW + s * SROW);
            int c = 31 + s - pj;
            row[c]     = k0;
            row[c - 1] = k1;
            row[c - 2] = k2;
            row[c - 3] = k3;
        }
    }
    __syncthreads();

    int A0 = n - 8 * q;
    int A1 = A0 + 16;
    int sh1 = (A1 + 9) & 7;
    int off1 = sh1 * SROW + (31 + sh1 - A1) * 2;
    int off0;
    if (A0 >= -8) {
        int sh0 = (A0 + 9) & 7;
        off0 = sh0 * SROW + (31 + sh0 - A0) * 2;
    } else {
        off0 = 80;
    }
    int boff = nn * 64 + q * 16;
    const char* zptr = smem + 80;

    f32x4 acc0[4], acc1[4];
    #pragma unroll
    for (int ii = 0; ii < 4; ++ii) {
        acc0[ii] = (f32x4){0.f, 0.f, 0.f, 0.f};
        acc1[ii] = (f32x4){0.f, 0.f, 0.f, 0.f};
    }

    #pragma unroll
    for (int j = 0; j < 8; ++j) {
        if (j <= 2 * wv + 1) {
            const char* krow = smem + j * KROW;
            short8 a0 = *(const short8*)(krow + off0);
            short8 a1 = *(const short8*)(krow + off1);
            {
                int u = 2 * wv + hi - j;
                const char* bp = (u >= 0) ? (xtl + u * 512 + boff) : zptr;
                short8 bb = *(const short8*)bp;
                acc0[0] = __builtin_amdgcn_mfma_f32_16x16x32_bf16(a0, bb, acc0[0], 0, 0, 0);
                acc1[0] = __builtin_amdgcn_mfma_f32_16x16x32_bf16(a1, bb, acc1[0], 0, 0, 0);
            }
            #pragma unroll
            for (int ii = 1; ii < 4; ++ii) {
                int u = 2 * wv + 8 * ii + hi - j;
                short8 bb = *(const short8*)(xtl + u * 512 + boff);
                acc0[ii] = __builtin_amdgcn_mfma_f32_16x16x32_bf16(a0, bb, acc0[ii], 0, 0, 0);
                acc1[ii] = __builtin_amdgcn_mfma_f32_16x16x32_bf16(a1, bb, acc1[ii], 0, 0, 0);
            }
        }
    }
    #pragma unroll
    for (int b = 1; b <= 3; ++b) {
        #pragma unroll
        for (int m = 0; m < 8; ++m) {
            int di = 2 * wv + 8 * b - 6 + m;
            const char* krow = smem + di * KROW;
            short8 a0 = *(const short8*)(krow + off0);
            short8 a1 = *(const short8*)(krow + off1);
            #pragma unroll
            for (int ii = b; ii < 4; ++ii) {
                int u = 8 * (ii - b) + 6 + hi - m;
                const char* bp = ((ii == b) && (m == 7) && (hi == 0))
                                     ? zptr : (xtl + u * 512 + boff);
                short8 bb = *(const short8*)bp;
                acc0[ii] = __builtin_amdgcn_mfma_f32_16x16x32_bf16(a0, bb, acc0[ii], 0, 0, 0);
                acc1[ii] = __builtin_amdgcn_mfma_f32_16x16x32_bf16(a1, bb, acc1[ii], 0, 0, 0);
            }
        }
    }

    {
        uint16_t* base = ytb + ((size_t)(nn * 1024 + e)) * 1024 + q * 4;
        #pragma unroll
        for (int ii = 0; ii < 4; ++ii) {
            int ro = 2 * wv + 8 * ii + hi;
            uint2 w0 = make_uint2(packbf(acc0[ii][0], acc0[ii][1]),
                                  packbf(acc0[ii][2], acc0[ii][3]));
            uint2 w1 = make_uint2(packbf(acc1[ii][0], acc1[ii][1]),
                                  packbf(acc1[ii][2], acc1[ii][3]));
            *(uint2*)(base + ro * 32)      = w0;
            *(uint2*)(base + ro * 32 + 16) = w1;
        }
    }
}

// ---------------------------------------------------------------------------
// K_t2: out[p][b][e] = ytb[b][e][p] + x[p][b][e]*omega[e]
// ---------------------------------------------------------------------------
__global__ __launch_bounds__(256) void k_t2(const uint16_t* __restrict__ ytb,
                                            const float* __restrict__ x,
                                            const float* __restrict__ omega,
                                            float* __restrict__ out) {
    __shared__ float lds[32 * 130];   // [e][pl], pad 130 (8B-aligned float2)
    int e0 = blockIdx.x * 32, p0 = blockIdx.y * 128, b = blockIdx.z;
    int t = threadIdx.x;
    {
        int a = t >> 3, c = t & 7;          // a: e-row 0..31, c: 128B chunk
        const uint16_t* src = ytb + (size_t)(b * 1024 + e0 + a) * 1024 + p0;
        float* dst = lds + a * 130;
        #pragma unroll
        for (int rep = 0; rep < 2; ++rep) {
            int off = (c + rep * 8) * 8;    // p offset, 8 p per uint4
            uint4 v = *(const uint4*)(src + off);
            uint32_t ww[4] = {v.x, v.y, v.z, v.w};
            #pragma unroll
            for (int k = 0; k < 4; ++k) {
                float2 f;
                f.x = bf2f((uint16_t)(ww[k] & 0xFFFFu));
                f.y = bf2f((uint16_t)(ww[k] >> 16));
                *(float2*)(dst + off + k * 2) = f;
            }
        }
    }
    __syncthreads();
    int pl = t >> 1, eh = (t & 1) * 16;
    int p = p0 + pl;
    const float* xs = x + ((size_t)(p * 8 + b)) * 1024 + e0 + eh;
    float* os = out + ((size_t)(p * 8 + b)) * 1024 + e0 + eh;
    #pragma unroll
    for (int qq = 0; qq < 4; ++qq) {
        float4 xv = *(const float4*)(xs + qq * 4);
        int eb = eh + qq * 4;
        float4 ov;
        ov.x = lds[(eb + 0) * 130 + pl] + xv.x * omega[e0 + eb + 0];
        ov.y = lds[(eb + 1) * 130 + pl] + xv.y * omega[e0 + eb + 1];
        ov.z = lds[(eb + 2) * 130 + pl] + xv.z * omega[e0 + eb + 2];
        ov.w = lds[(eb + 3) * 130 + pl] + xv.w * omega[e0 + eb + 3];
        *(float4*)(os + qq * 4) = ov;
    }
}

// ---------------------------------------------------------------------------
extern "C" void kernel_launch(void* const* d_in, const int* in_sizes, int n_in,
                              void* d_out, int out_size, void* d_ws, size_t ws_size,
                              hipStream_t stream) {
    (void)in_sizes; (void)n_in; (void)out_size; (void)ws_size;
    const float* x   = (const float*)d_in[0];
    const float* A   = (const float*)d_in[1];
    const float* B1  = (const float*)d_in[2];
    const float* B2  = (const float*)d_in[3];
    const float* C1  = (const float*)d_in[4];
    const float* C2  = (const float*)d_in[5];
    const float* omg = (const float*)d_in[6];
    const float* om  = (const float*)d_in[7];
    float* out = (float*)d_out;

    float* ws  = (float*)d_ws;
    uint16_t* xtb  = (uint16_t*)ws;                     // 16 MB
    uint16_t* kd4b = (uint16_t*)(ws + 4194304);         // 8 MB
    uint16_t* ytb  = (uint16_t*)(ws + 6291456);         // 16 MB
    float* w       = ws + 10485760;                     // 8 MB

    k_front4<<<4096, 256, 0, stream>>>(x, xtb, om, A, B1, B2, w);
    k_kd    <<<dim3(64, 8), 256, 0, stream>>>(w, C1, C2, kd4b);
    k_conv  <<<1024, 256, 0, stream>>>(xtb, kd4b, ytb);
    k_t2    <<<dim3(32, 8, 8), 256, 0, stream>>>(ytb, x, omg, out);
}